// Round 10
// baseline (1567.455 us; speedup 1.0000x reference)
//
#include <hip/hip_runtime.h>
#include <stdint.h>

#define HID 64
#define INDIM 128
#define BNODES 128     // nodes per bucket (dst>>7)
#define NBLK 512       // binsort producer blocks
#define EPBCAP 3200    // max edges per binsort block (actual 3125)
#define SCW 1024       // bucket-scan width (>= nbuck=782)

typedef __attribute__((ext_vector_type(8))) short bf16x8;
typedef __attribute__((ext_vector_type(4))) float f32x4;
typedef __attribute__((ext_vector_type(2))) float f32x2;

__host__ __device__ __forceinline__ void tf2x32(uint32_t k0, uint32_t k1,
                                                uint32_t x0, uint32_t x1,
                                                uint32_t& o0, uint32_t& o1) {
  uint32_t ks2 = k0 ^ k1 ^ 0x1BD11BDAu;
#define ROTL(v, r) (((v) << (r)) | ((v) >> (32 - (r))))
#define RND(r) { x0 += x1; x1 = ROTL(x1, r); x1 ^= x0; }
  x0 += k0; x1 += k1;
  RND(13) RND(15) RND(26) RND(6)
  x0 += k1; x1 += ks2 + 1u;
  RND(17) RND(29) RND(16) RND(24)
  x0 += ks2; x1 += k0 + 2u;
  RND(13) RND(15) RND(26) RND(6)
  x0 += k0; x1 += k1 + 3u;
  RND(17) RND(29) RND(16) RND(24)
  x0 += k1; x1 += ks2 + 4u;
  RND(13) RND(15) RND(26) RND(6)
  x0 += ks2; x1 += k0 + 5u;
  o0 = x0; o1 = x1;
#undef RND
#undef ROTL
}

__device__ __forceinline__ float tf_uniform(uint32_t ka, uint32_t kb, uint32_t j) {
  uint32_t o0, o1;
  tf2x32(ka, kb, 0u, j, o0, o1);
  uint32_t bits = o0 ^ o1;
  uint32_t f = (bits >> 9) | 0x3f800000u;
  return __uint_as_float(f) - 1.0f;
}

__device__ __forceinline__ unsigned short f2bf(float f) {
  uint32_t x = __float_as_uint(f);
  uint32_t r = (x + 0x7fffu + ((x >> 16) & 1u)) >> 16;   // RNE
  return (unsigned short)r;
}

__device__ __forceinline__ float bf2f_lo(uint32_t u) { return __uint_as_float(u << 16); }
__device__ __forceinline__ float bf2f_hi(uint32_t u) { return __uint_as_float(u & 0xffff0000u); }

__device__ __forceinline__ unsigned char f2fp8(float v) {
  return (unsigned char)(__builtin_amdgcn_cvt_pk_fp8_f32(v, 0.f, 0, false) & 0xff);
}

// K1: per-block counting sort of edges by bucket (dst>>7). No global atomics.
// packed entry: (src<<7) | (dst&127)  (src<2^17 -> 24 bits)
__global__ __launch_bounds__(256) void binsort_k(const int* __restrict__ src,
                                                 const int* __restrict__ dst,
                                                 uint32_t* __restrict__ sorted,
                                                 int* __restrict__ blockoff,
                                                 int E, int EPB, int nbuck) {
  __shared__ uint32_t lbuf[EPBCAP];
  __shared__ int ha[SCW], hb[SCW], cursor[SCW];
  int b = blockIdx.x, t = threadIdx.x;
  int e0 = b * EPB;
  int e1 = e0 + EPB; if (e1 > E) e1 = E;
  int m = e1 - e0;
  ha[t] = 0; ha[t + 256] = 0; ha[t + 512] = 0; ha[t + 768] = 0;
  __syncthreads();
  for (int i = t; i < m; i += 256) atomicAdd(&ha[dst[e0 + i] >> 7], 1);
  __syncthreads();
  int* cur = ha; int* nxt = hb;
  for (int off = 1; off < SCW; off <<= 1) {
    int v0 = cur[t] + ((t >= off) ? cur[t - off] : 0);
    int i1 = t + 256, i2 = t + 512, i3 = t + 768;
    int v1 = cur[i1] + ((i1 >= off) ? cur[i1 - off] : 0);
    int v2 = cur[i2] + ((i2 >= off) ? cur[i2 - off] : 0);
    int v3 = cur[i3] + ((i3 >= off) ? cur[i3 - off] : 0);
    __syncthreads();
    nxt[t] = v0; nxt[i1] = v1; nxt[i2] = v2; nxt[i3] = v3;
    __syncthreads();
    int* tmp = cur; cur = nxt; nxt = tmp;
  }
  int* bo = blockoff + (size_t)b * (nbuck + 1);
  for (int i = t; i < nbuck; i += 256) {
    int ex = (i == 0) ? 0 : cur[i - 1];
    cursor[i] = ex;
    bo[i] = ex;
  }
  if (t == 0) bo[nbuck] = m;
  __syncthreads();
  for (int i = t; i < m; i += 256) {
    int d = dst[e0 + i], s = src[e0 + i];
    int pos = atomicAdd(&cursor[d >> 7], 1);
    lbuf[pos] = ((uint32_t)s << 7) | (uint32_t)(d & 127);
  }
  __syncthreads();
  for (int i = t; i < m; i += 256) sorted[e0 + i] = lbuf[i];
}

// K2a: per bucket k, exclusive scan over producer blocks of segment lengths.
__global__ __launch_bounds__(NBLK) void boff_k(const int* __restrict__ blockoff,
                                               int* __restrict__ destoff,
                                               int* __restrict__ totals, int nbuck) {
  __shared__ int sa[NBLK], sb[NBLK];
  int k = blockIdx.x, t = threadIdx.x;   // t = producer block
  const int stride = nbuck + 1;
  int len = blockoff[(size_t)t * stride + k + 1] - blockoff[(size_t)t * stride + k];
  sa[t] = len;
  __syncthreads();
  int* cur = sa; int* nxt = sb;
  for (int off = 1; off < NBLK; off <<= 1) {
    int v = cur[t] + ((t >= off) ? cur[t - off] : 0);
    __syncthreads();
    nxt[t] = v;
    __syncthreads();
    int* tmp = cur; cur = nxt; nxt = tmp;
  }
  destoff[(size_t)t * nbuck + k] = cur[t] - len;
  if (t == NBLK - 1) totals[k] = cur[t];
}

// K2b: exclusive scan of bucket totals -> bucketstart; zero colsum.
__global__ __launch_bounds__(1024) void bscan_k(const int* __restrict__ totals,
                                                int* __restrict__ bucketstart,
                                                float* __restrict__ colsum,
                                                int nbuck, int E) {
  __shared__ int sa[SCW], sb[SCW];
  int t = threadIdx.x;
  int v = (t < nbuck) ? totals[t] : 0;
  sa[t] = v;
  __syncthreads();
  int* cur = sa; int* nxt = sb;
  for (int off = 1; off < SCW; off <<= 1) {
    int x = cur[t] + ((t >= off) ? cur[t - off] : 0);
    __syncthreads();
    nxt[t] = x;
    __syncthreads();
    int* tmp = cur; cur = nxt; nxt = tmp;
  }
  if (t < nbuck) bucketstart[t] = cur[t] - v;
  if (t == 0) bucketstart[nbuck] = E;
  if (t < HID) colsum[t] = 0.f;
}

// K2c: copy each block's bucket segments to global bucket-sorted positions.
__global__ __launch_bounds__(256) void scatter2_k(const uint32_t* __restrict__ sorted,
                                                  const int* __restrict__ blockoff,
                                                  const int* __restrict__ destoff,
                                                  const int* __restrict__ bucketstart,
                                                  uint32_t* __restrict__ sorted2,
                                                  int EPB, int nbuck) {
  int b = blockIdx.x, t = threadIdx.x;
  const uint32_t* chunk = sorted + (size_t)b * EPB;
  const int* bo = blockoff + (size_t)b * (nbuck + 1);
  for (int k = t; k < nbuck; k += 256) {
    int ss = bo[k], se = bo[k + 1];
    int dd = bucketstart[k] + destoff[(size_t)b * nbuck + k];
    for (int i = ss; i < se; i++) sorted2[dd + (i - ss)] = chunk[i];
  }
}

// K3: per-bucket degree histogram -> norm (replaces csrbuild; no csr needed)
__global__ __launch_bounds__(256) void bnorm_k(const uint32_t* __restrict__ sorted2,
                                               const int* __restrict__ bucketstart,
                                               float* __restrict__ norm, int n) {
  __shared__ int cnt[BNODES];
  int k = blockIdx.x, t = threadIdx.x;
  if (t < BNODES) cnt[t] = 0;
  __syncthreads();
  int s0 = bucketstart[k], s1 = bucketstart[k + 1];
  for (int i = s0 + t; i < s1; i += 256) atomicAdd(&cnt[sorted2[i] & 127u], 1);
  __syncthreads();
  int node = k * BNODES + t;
  if (t < BNODES && node < n) norm[node] = rsqrtf((float)(cnt[t] + 1));
}

// convert w1,w2 to transposed bf16: w1t[c*128+k], w2t[c*64+k]
__global__ __launch_bounds__(256) void wcvt_k(const float* __restrict__ w1,
                                              const float* __restrict__ w2,
                                              unsigned short* __restrict__ w1t,
                                              unsigned short* __restrict__ w2t) {
  int i = blockIdx.x * 256 + threadIdx.x;
  if (i < INDIM * HID) {
    int c = i >> 7, k = i & 127;
    w1t[i] = f2bf(w1[k * HID + c]);
  } else {
    int j = i - INDIM * HID;
    if (j < HID * HID) {
      int c = j >> 6, k = j & 63;
      w2t[j] = f2bf(w2[k * HID + c]);
    }
  }
}

// MFMA gemm1: h0 = fp8(norm * (feat @ w1)). One wave per 16-node strip.
__global__ __launch_bounds__(256) void gemm1(const float* __restrict__ feat,
                                             const unsigned short* __restrict__ w1t,
                                             const float* __restrict__ norm,
                                             unsigned char* __restrict__ h0, int n) {
  int t = threadIdx.x;
  int wv = t >> 6, lane = t & 63;
  int strip = blockIdx.x * 4 + wv;
  if (strip * 16 >= n) return;
  int m = lane & 15, q = lane >> 4;
  bf16x8 Bf[4][4];
#pragma unroll
  for (int kc = 0; kc < 4; kc++)
#pragma unroll
    for (int ct = 0; ct < 4; ct++)
      Bf[kc][ct] = *(const bf16x8*)(w1t + (ct * 16 + m) * INDIM + kc * 32 + q * 8);
  const float* arow = feat + (size_t)(strip * 16 + m) * INDIM;
  bf16x8 Af[4];
#pragma unroll
  for (int kc = 0; kc < 4; kc++) {
    const float* pa = arow + kc * 32 + q * 8;
    bf16x8 a;
#pragma unroll
    for (int j = 0; j < 8; j++) a[j] = (short)f2bf(pa[j]);
    Af[kc] = a;
  }
  f32x4 acc[4] = {{0.f,0.f,0.f,0.f},{0.f,0.f,0.f,0.f},{0.f,0.f,0.f,0.f},{0.f,0.f,0.f,0.f}};
#pragma unroll
  for (int kc = 0; kc < 4; kc++)
#pragma unroll
    for (int ct = 0; ct < 4; ct++)
      acc[ct] = __builtin_amdgcn_mfma_f32_16x16x32_bf16(Af[kc], Bf[kc][ct], acc[ct], 0, 0, 0);
#pragma unroll
  for (int r = 0; r < 4; r++) {
    int row = strip * 16 + q * 4 + r;
    float nm = norm[row];
#pragma unroll
    for (int ct = 0; ct < 4; ct++)
      h0[(size_t)row * HID + ct * 16 + m] = f2fp8(acc[ct][r] * nm);
  }
}

// Bucket-parallel gather: block = 128-node bucket; edges streamed from sorted2;
// LDS f32 accumulation (ds_add_f32). 4 edges per wave-instr, 16 lanes/edge.
// MODE 0: fused relu/dropout/prescale -> fp8 out. MODE 1: raw sums -> bf16 out.
template <int MODE>
__global__ __launch_bounds__(256) void bgather_k(const uint32_t* __restrict__ h8,
                                                 void* __restrict__ outp,
                                                 const uint32_t* __restrict__ sorted2,
                                                 const int* __restrict__ bucketstart,
                                                 const float* __restrict__ norm,
                                                 int n, uint32_t ka, uint32_t kb) {
  __shared__ float agg[BNODES * 65];       // +1 pad: bank = (node+col)%32
  int bk = blockIdx.x, t = threadIdx.x;
  for (int i = t; i < BNODES * 65; i += 256) agg[i] = 0.f;
  __syncthreads();
  int s0 = bucketstart[bk], s1 = bucketstart[bk + 1];
  int M = s1 - s0;
  int w = t >> 6, lane = t & 63;
  int es = lane >> 4;                      // edge sub 0..3
  int j = lane & 15;                       // row uint 0..15 (cols 4j..4j+3)
  for (int base = w * 4; base < M; base += 16) {
    int e = base + es;
    if (e < M) {
      uint32_t pe = sorted2[s0 + e];
      int srcn = (int)(pe >> 7);
      int dl = (int)(pe & 127u);
      uint32_t u = h8[(size_t)srcn * 16 + j];
      f32x2 lo = __builtin_amdgcn_cvt_pk_f32_fp8((int)u, false);
      f32x2 hi = __builtin_amdgcn_cvt_pk_f32_fp8((int)u, true);
      float* a = &agg[dl * 65 + 4 * j];
      atomicAdd(a + 0, lo.x);
      atomicAdd(a + 1, lo.y);
      atomicAdd(a + 2, hi.x);
      atomicAdd(a + 3, hi.y);
    }
  }
  __syncthreads();
  // epilogue: (node, quad) pairs; quad q covers cols 4q..4q+3
  int node0 = bk * BNODES;
#pragma unroll
  for (int i = 0; i < 8; i++) {
    int p = t + (i << 8);                  // 0..2047
    int nd = p >> 4, q = p & 15;
    int node = node0 + nd;
    if (node >= n) continue;
    uint32_t su = h8[(size_t)node * 16 + q];   // self loop
    f32x2 slo = __builtin_amdgcn_cvt_pk_f32_fp8((int)su, false);
    f32x2 shi = __builtin_amdgcn_cvt_pk_f32_fp8((int)su, true);
    const float* a = &agg[nd * 65 + 4 * q];
    float a0 = a[0] + slo.x, a1 = a[1] + slo.y;
    float a2 = a[2] + shi.x, a3 = a[3] + shi.y;
    if (MODE == 0) {
      float nm = norm[node];
      uint32_t j0 = (uint32_t)node * 64u + (uint32_t)(4 * q);
      float u0 = tf_uniform(ka, kb, j0);
      float u1 = tf_uniform(ka, kb, j0 + 1u);
      float u2 = tf_uniform(ka, kb, j0 + 2u);
      float u3 = tf_uniform(ka, kb, j0 + 3u);
      float s2 = 2.f * nm;
      float v0 = (u0 < 0.5f) ? fmaxf(a0 * nm, 0.f) * s2 : 0.f;
      float v1 = (u1 < 0.5f) ? fmaxf(a1 * nm, 0.f) * s2 : 0.f;
      float v2 = (u2 < 0.5f) ? fmaxf(a2 * nm, 0.f) * s2 : 0.f;
      float v3 = (u3 < 0.5f) ? fmaxf(a3 * nm, 0.f) * s2 : 0.f;
      int o = __builtin_amdgcn_cvt_pk_fp8_f32(v0, v1, 0, false);
      o = __builtin_amdgcn_cvt_pk_fp8_f32(v2, v3, o, true);
      ((uint32_t*)outp)[(size_t)node * 16 + q] = (uint32_t)o;
    } else {
      uint2 wv2;
      wv2.x = (uint32_t)f2bf(a0) | ((uint32_t)f2bf(a1) << 16);
      wv2.y = (uint32_t)f2bf(a2) | ((uint32_t)f2bf(a3) << 16);
      ((uint2*)outp)[(size_t)node * 16 + q] = wv2;
    }
  }
}

// MFMA gemm2: h2 = bf16 dropout(relu(norm * (aggbf @ w2))). One wave/strip.
__global__ __launch_bounds__(256) void gemm2(const unsigned short* __restrict__ aggbf,
                                             const unsigned short* __restrict__ w2t,
                                             const float* __restrict__ norm,
                                             unsigned short* __restrict__ h2, int n,
                                             uint32_t ka, uint32_t kb) {
  int t = threadIdx.x;
  int wv = t >> 6, lane = t & 63;
  int strip = blockIdx.x * 4 + wv;
  if (strip * 16 >= n) return;
  int m = lane & 15, q = lane >> 4;
  bf16x8 Bf[2][4];
#pragma unroll
  for (int kc = 0; kc < 2; kc++)
#pragma unroll
    for (int ct = 0; ct < 4; ct++)
      Bf[kc][ct] = *(const bf16x8*)(w2t + (ct * 16 + m) * HID + kc * 32 + q * 8);
  const unsigned short* arow = aggbf + (size_t)(strip * 16 + m) * HID;
  bf16x8 Af[2];
#pragma unroll
  for (int kc = 0; kc < 2; kc++)
    Af[kc] = *(const bf16x8*)(arow + kc * 32 + q * 8);
  f32x4 acc[4] = {{0.f,0.f,0.f,0.f},{0.f,0.f,0.f,0.f},{0.f,0.f,0.f,0.f},{0.f,0.f,0.f,0.f}};
#pragma unroll
  for (int kc = 0; kc < 2; kc++)
#pragma unroll
    for (int ct = 0; ct < 4; ct++)
      acc[ct] = __builtin_amdgcn_mfma_f32_16x16x32_bf16(Af[kc], Bf[kc][ct], acc[ct], 0, 0, 0);
#pragma unroll
  for (int r = 0; r < 4; r++) {
    int row = strip * 16 + q * 4 + r;
    float nm = norm[row];
#pragma unroll
    for (int ct = 0; ct < 4; ct++) {
      int col = ct * 16 + m;
      float v = fmaxf(acc[ct][r] * nm, 0.f);
      float u = tf_uniform(ka, kb, (uint32_t)row * 64u + (uint32_t)col);
      v = (u < 0.5f) ? v * 2.f : 0.f;
      h2[(size_t)row * HID + col] = f2bf(v);
    }
  }
}

// column sums over bf16 h2 (read as packed uints)
__global__ __launch_bounds__(256) void colsum_k(const uint32_t* __restrict__ h2u,
                                                float* __restrict__ colsum, int n) {
  int t = threadIdx.x;
  int cp = t & 31;                // column pair
  int rg = t >> 5;                // 8 row groups
  float sx = 0.f, sy = 0.f;
  for (int r = blockIdx.x * 8 + rg; r < n; r += gridDim.x * 8) {
    uint32_t u = h2u[(size_t)r * 32 + cp];
    sx += bf2f_lo(u); sy += bf2f_hi(u);
  }
  __shared__ float red[8][HID];
  red[rg][2 * cp] = sx; red[rg][2 * cp + 1] = sy;
  __syncthreads();
  if (t < HID) {
    float v = 0.f;
#pragma unroll
    for (int i = 0; i < 8; i++) v += red[i][t];
    atomicAdd(&colsum[t], v);
  }
}

__global__ __launch_bounds__(128) void final_k(const uint32_t* __restrict__ h2u,
                                               const float* __restrict__ colsum,
                                               const float* __restrict__ conv_w,
                                               const float* __restrict__ conv_b,
                                               const float* __restrict__ ref_radius,
                                               float* __restrict__ out, int n) {
  __shared__ float rows[128 * 67];
  __shared__ float omean[124];
  __shared__ float cm[HID];
  int t = threadIdx.x;
  int node0 = blockIdx.x * 128;
  if (t < HID) cm[t] = colsum[t] * (1.0f / (float)n);
  for (int idx = t; idx < 128 * 32; idx += 128) {
    int r = idx >> 5, cpi = idx & 31;
    int node = node0 + r;
    uint32_t u = (node < n) ? h2u[(size_t)node * 32 + cpi] : 0u;
    rows[r * 67 + 2 * cpi] = bf2f_lo(u);
    rows[r * 67 + 2 * cpi + 1] = bf2f_hi(u);
  }
  __syncthreads();
  if (t < 124) {
    int o = t / 62, i = t % 62;
    omean[t] = conv_b[o] + conv_w[o * 3] * cm[i] + conv_w[o * 3 + 1] * cm[i + 1] +
               conv_w[o * 3 + 2] * cm[i + 2];
  }
  __syncthreads();
  int node = node0 + t;
  if (node < n) {
    float r0[HID];
#pragma unroll
    for (int k = 0; k < HID; k++) r0[k] = rows[t * 67 + k];
    float w00 = conv_w[0], w01 = conv_w[1], w02 = conv_w[2];
    float w10 = conv_w[3], w11 = conv_w[4], w12 = conv_w[5];
    float b0 = conv_b[0], b1 = conv_b[1];
    float acc = 0.f;
#pragma unroll
    for (int i = 0; i < 62; i++) {
      float y0 = b0 + w00 * r0[i] + w01 * r0[i + 1] + w02 * r0[i + 2];
      float d0 = y0 - omean[i] + 1e-6f;
      acc += d0 * d0;
      float y1 = b1 + w10 * r0[i] + w11 * r0[i + 1] + w12 * r0[i + 2];
      float d1 = y1 - omean[62 + i] + 1e-6f;
      acc += d1 * d1;
    }
    float radius = sqrtf(acc);
    float dis = fminf(fmaxf(radius - ref_radius[0], 1e-4f), 1.f - 1e-4f);
    out[node] = dis;
  }
  if (blockIdx.x == 0 && t == 0) out[n] = ref_radius[0];
}

extern "C" void kernel_launch(void* const* d_in, const int* in_sizes, int n_in,
                              void* d_out, int out_size, void* d_ws, size_t ws_size,
                              hipStream_t stream) {
  const float* feat = (const float*)d_in[0];
  const float* w1 = (const float*)d_in[1];
  const float* w2 = (const float*)d_in[2];
  const float* conv_w = (const float*)d_in[3];
  const float* conv_b = (const float*)d_in[4];
  const float* ref_radius = (const float*)d_in[5];
  const int* src = (const int*)d_in[6];
  const int* dst = (const int*)d_in[7];
  int n = in_sizes[0] / INDIM;
  int E = in_sizes[6];
  float* out = (float*)d_out;

  int nbuck = (n + BNODES - 1) >> 7;       // 782 buckets of 128 nodes
  int EPB = (E + NBLK - 1) / NBLK;         // 3125 edges per binsort block

  char* p = (char*)d_ws;
  auto carve = [&](size_t bytes) { void* r = (void*)p; p += (bytes + 255) & ~(size_t)255; return r; };
  float* norm = (float*)carve((size_t)n * 4);
  float* colsum = (float*)carve(HID * 4);
  int* bucketstart = (int*)carve(((size_t)nbuck + 1) * 4);
  int* totals = (int*)carve((size_t)nbuck * 4);
  int* blockoff = (int*)carve((size_t)NBLK * (nbuck + 1) * 4);
  int* destoff = (int*)carve((size_t)NBLK * nbuck * 4);
  uint32_t* sorted = (uint32_t*)carve((size_t)E * 4);
  uint32_t* sorted2 = (uint32_t*)carve((size_t)E * 4);
  unsigned short* w1t = (unsigned short*)carve((size_t)INDIM * HID * 2);
  unsigned short* w2t = (unsigned short*)carve((size_t)HID * HID * 2);
  unsigned char* H0f8 = (unsigned char*)carve((size_t)n * HID);
  unsigned char* Tf8 = (unsigned char*)carve((size_t)n * HID);
  unsigned short* Abf = (unsigned short*)carve((size_t)n * HID * 2);
  unsigned short* H2bf = (unsigned short*)carve((size_t)n * HID * 2);

  uint32_t k1a, k1b, k2a, k2b;
  tf2x32(0u, 42u, 0u, 0u, k1a, k1b);
  tf2x32(0u, 42u, 0u, 1u, k2a, k2b);

  int stripB = ((n + 15) / 16 + 3) / 4;    // wave per 16-node strip

  binsort_k<<<NBLK, 256, 0, stream>>>(src, dst, sorted, blockoff, E, EPB, nbuck);
  boff_k<<<nbuck, NBLK, 0, stream>>>(blockoff, destoff, totals, nbuck);
  bscan_k<<<1, 1024, 0, stream>>>(totals, bucketstart, colsum, nbuck, E);
  scatter2_k<<<NBLK, 256, 0, stream>>>(sorted, blockoff, destoff, bucketstart, sorted2, EPB, nbuck);
  bnorm_k<<<nbuck, 256, 0, stream>>>(sorted2, bucketstart, norm, n);
  wcvt_k<<<(INDIM * HID + HID * HID + 255) / 256, 256, 0, stream>>>(w1, w2, w1t, w2t);
  gemm1<<<stripB, 256, 0, stream>>>(feat, w1t, norm, H0f8, n);
  bgather_k<0><<<nbuck, 256, 0, stream>>>((const uint32_t*)H0f8, Tf8, sorted2, bucketstart, norm, n, k1a, k1b);
  bgather_k<1><<<nbuck, 256, 0, stream>>>((const uint32_t*)Tf8, Abf, sorted2, bucketstart, norm, n, 0u, 0u);
  gemm2<<<stripB, 256, 0, stream>>>(Abf, w2t, norm, H2bf, n, k2a, k2b);
  colsum_k<<<256, 256, 0, stream>>>((const uint32_t*)H2bf, colsum, n);
  final_k<<<(n + 127) / 128, 128, 0, stream>>>((const uint32_t*)H2bf, colsum, conv_w, conv_b, ref_radius, out, n);
}

// Round 11
// 297.604 us; speedup vs baseline: 5.2669x; 5.2669x over previous
//
#include <hip/hip_runtime.h>
#include <stdint.h>

#define HID 64
#define INDIM 128
#define NBK 512        // scan width >= NB (391) and >= NBLK (512)
#define NBLK 512       // binsort producer blocks
#define EPBCAP 3200    // max edges per binsort block (actual 3125)
#define BK3CAP 8192    // max edges per bucket (mean ~4092, sd ~64)

typedef __attribute__((ext_vector_type(8))) short bf16x8;
typedef __attribute__((ext_vector_type(4))) float f32x4;
typedef __attribute__((ext_vector_type(2))) float f32x2;

__host__ __device__ __forceinline__ void tf2x32(uint32_t k0, uint32_t k1,
                                                uint32_t x0, uint32_t x1,
                                                uint32_t& o0, uint32_t& o1) {
  uint32_t ks2 = k0 ^ k1 ^ 0x1BD11BDAu;
#define ROTL(v, r) (((v) << (r)) | ((v) >> (32 - (r))))
#define RND(r) { x0 += x1; x1 = ROTL(x1, r); x1 ^= x0; }
  x0 += k0; x1 += k1;
  RND(13) RND(15) RND(26) RND(6)
  x0 += k1; x1 += ks2 + 1u;
  RND(17) RND(29) RND(16) RND(24)
  x0 += ks2; x1 += k0 + 2u;
  RND(13) RND(15) RND(26) RND(6)
  x0 += k0; x1 += k1 + 3u;
  RND(17) RND(29) RND(16) RND(24)
  x0 += k1; x1 += ks2 + 4u;
  RND(13) RND(15) RND(26) RND(6)
  x0 += ks2; x1 += k0 + 5u;
  o0 = x0; o1 = x1;
#undef RND
#undef ROTL
}

__device__ __forceinline__ float tf_uniform(uint32_t ka, uint32_t kb, uint32_t j) {
  uint32_t o0, o1;
  tf2x32(ka, kb, 0u, j, o0, o1);
  uint32_t bits = o0 ^ o1;
  uint32_t f = (bits >> 9) | 0x3f800000u;
  return __uint_as_float(f) - 1.0f;
}

__device__ __forceinline__ unsigned short f2bf(float f) {
  uint32_t x = __float_as_uint(f);
  uint32_t r = (x + 0x7fffu + ((x >> 16) & 1u)) >> 16;   // RNE
  return (unsigned short)r;
}

__device__ __forceinline__ float bf2f_lo(uint32_t u) { return __uint_as_float(u << 16); }
__device__ __forceinline__ float bf2f_hi(uint32_t u) { return __uint_as_float(u & 0xffff0000u); }

__device__ __forceinline__ unsigned char f2fp8(float v) {
  return (unsigned char)(__builtin_amdgcn_cvt_pk_fp8_f32(v, 0.f, 0, false) & 0xff);
}

// K1: per-block counting sort of edges by bucket (dst>>8). No global atomics.
__global__ __launch_bounds__(256) void binsort_k(const int* __restrict__ src,
                                                 const int* __restrict__ dst,
                                                 uint32_t* __restrict__ sorted,
                                                 int* __restrict__ blockoff,
                                                 int E, int EPB, int NB) {
  __shared__ uint32_t lbuf[EPBCAP];
  __shared__ int ha[NBK], hb[NBK], cursor[NBK];
  int b = blockIdx.x, t = threadIdx.x;
  int e0 = b * EPB;
  int e1 = e0 + EPB; if (e1 > E) e1 = E;
  int m = e1 - e0;
  ha[t] = 0; ha[t + 256] = 0;
  __syncthreads();
  for (int i = t; i < m; i += 256) atomicAdd(&ha[dst[e0 + i] >> 8], 1);
  __syncthreads();
  int* cur = ha; int* nxt = hb;
  for (int off = 1; off < 512; off <<= 1) {
    int i0 = t, i1 = t + 256;
    int v0 = cur[i0] + ((i0 >= off) ? cur[i0 - off] : 0);
    int v1 = cur[i1] + ((i1 >= off) ? cur[i1 - off] : 0);
    __syncthreads();
    nxt[i0] = v0; nxt[i1] = v1;
    __syncthreads();
    int* tmp = cur; cur = nxt; nxt = tmp;
  }
  int* bo = blockoff + (size_t)b * (NB + 1);
  for (int i = t; i < NB; i += 256) {
    int ex = (i == 0) ? 0 : cur[i - 1];
    cursor[i] = ex;
    bo[i] = ex;
  }
  if (t == 0) bo[NB] = m;
  __syncthreads();
  for (int i = t; i < m; i += 256) {
    int d = dst[e0 + i], s = src[e0 + i];
    int pos = atomicAdd(&cursor[d >> 8], 1);
    lbuf[pos] = ((uint32_t)s << 8) | (uint32_t)(d & 255);
  }
  __syncthreads();
  for (int i = t; i < m; i += 256) sorted[e0 + i] = lbuf[i];
}

// K2a: per bucket k, exclusive scan over producer blocks of segment lengths.
__global__ __launch_bounds__(NBLK) void boff_k(const int* __restrict__ blockoff,
                                               int* __restrict__ destoff,
                                               int* __restrict__ totals, int NB) {
  __shared__ int sa[NBK], sb[NBK];
  int k = blockIdx.x, t = threadIdx.x;   // t = producer block
  const int stride = NB + 1;
  int len = blockoff[(size_t)t * stride + k + 1] - blockoff[(size_t)t * stride + k];
  sa[t] = len;
  __syncthreads();
  int* cur = sa; int* nxt = sb;
  for (int off = 1; off < NBLK; off <<= 1) {
    int v = cur[t] + ((t >= off) ? cur[t - off] : 0);
    __syncthreads();
    nxt[t] = v;
    __syncthreads();
    int* tmp = cur; cur = nxt; nxt = tmp;
  }
  destoff[(size_t)t * NB + k] = cur[t] - len;
  if (t == NBLK - 1) totals[k] = cur[t];
}

// K2b: exclusive scan of bucket totals -> bucketstart; zero colsum.
__global__ __launch_bounds__(512) void bscan_k(const int* __restrict__ totals,
                                               int* __restrict__ bucketstart,
                                               float* __restrict__ colsum,
                                               int NB, int E) {
  __shared__ int sa[NBK], sb[NBK];
  int t = threadIdx.x;
  int v = (t < NB) ? totals[t] : 0;
  sa[t] = v;
  __syncthreads();
  int* cur = sa; int* nxt = sb;
  for (int off = 1; off < 512; off <<= 1) {
    int x = cur[t] + ((t >= off) ? cur[t - off] : 0);
    __syncthreads();
    nxt[t] = x;
    __syncthreads();
    int* tmp = cur; cur = nxt; nxt = tmp;
  }
  if (t < NB) bucketstart[t] = cur[t] - v;
  if (t == 0) bucketstart[NB] = E;
  if (t < HID) colsum[t] = 0.f;
}

// K2c: copy each block's bucket segments to global bucket-sorted positions.
__global__ __launch_bounds__(256) void scatter2_k(const uint32_t* __restrict__ sorted,
                                                  const int* __restrict__ blockoff,
                                                  const int* __restrict__ destoff,
                                                  const int* __restrict__ bucketstart,
                                                  uint32_t* __restrict__ sorted2,
                                                  int EPB, int NB) {
  int b = blockIdx.x, t = threadIdx.x;
  const uint32_t* chunk = sorted + (size_t)b * EPB;
  const int* bo = blockoff + (size_t)b * (NB + 1);
  for (int k = t; k < NB; k += 256) {
    int ss = bo[k], se = bo[k + 1];
    int dd = bucketstart[k] + destoff[(size_t)b * NB + k];
    for (int i = ss; i < se; i++) sorted2[dd + (i - ss)] = chunk[i];
  }
}

// K3: one block per bucket: coalesced read, LDS hist/scan, emit rowstart/norm/csr.
__global__ __launch_bounds__(256) void csrbuild_k(const uint32_t* __restrict__ sorted2,
                                                  const int* __restrict__ bucketstart,
                                                  int* __restrict__ rowstart,
                                                  int* __restrict__ csr,
                                                  float* __restrict__ norm,
                                                  int NB, int n, int E) {
  __shared__ uint32_t ebuf[BK3CAP];
  __shared__ int sa[256], sb[256], cursor[256];
  int k = blockIdx.x, t = threadIdx.x;
  int s0 = bucketstart[k], s1 = bucketstart[k + 1];
  int M = s1 - s0;
  for (int i = t; i < M; i += 256) ebuf[i] = sorted2[s0 + i];
  cursor[t] = 0;
  __syncthreads();
  for (int i = t; i < M; i += 256) atomicAdd(&cursor[ebuf[i] & 255], 1);
  __syncthreads();
  int cnt = cursor[t];
  sa[t] = cnt;
  int* cur = sa; int* nxt = sb;
  __syncthreads();
  for (int off = 1; off < 256; off <<= 1) {
    int v = cur[t] + ((t >= off) ? cur[t - off] : 0);
    __syncthreads();
    nxt[t] = v;
    __syncthreads();
    int* tmp = cur; cur = nxt; nxt = tmp;
  }
  int localrow = cur[t] - cnt;
  int node = k * 256 + t;
  if (node < n) {
    rowstart[node] = s0 + localrow;
    norm[node] = rsqrtf((float)(cnt + 1));
  }
  if (k == NB - 1 && t == 255) rowstart[n] = E;
  cursor[t] = localrow;
  __syncthreads();
  for (int i = t; i < M; i += 256) {
    uint32_t pe = ebuf[i];
    int pos = atomicAdd(&cursor[pe & 255], 1);
    csr[s0 + pos] = (int)(pe >> 8);
  }
}

// convert w1,w2 to transposed bf16: w1t[c*128+k], w2t[c*64+k]
__global__ __launch_bounds__(256) void wcvt_k(const float* __restrict__ w1,
                                              const float* __restrict__ w2,
                                              unsigned short* __restrict__ w1t,
                                              unsigned short* __restrict__ w2t) {
  int i = blockIdx.x * 256 + threadIdx.x;
  if (i < INDIM * HID) {
    int c = i >> 7, k = i & 127;
    w1t[i] = f2bf(w1[k * HID + c]);
  } else {
    int j = i - INDIM * HID;
    if (j < HID * HID) {
      int c = j >> 6, k = j & 63;
      w2t[j] = f2bf(w2[k * HID + c]);
    }
  }
}

// MFMA gemm1: h0 = fp8(norm * (feat @ w1)). One wave per 16-node strip.
__global__ __launch_bounds__(256) void gemm1(const float* __restrict__ feat,
                                             const unsigned short* __restrict__ w1t,
                                             const float* __restrict__ norm,
                                             unsigned char* __restrict__ h0, int n) {
  int t = threadIdx.x;
  int wv = t >> 6, lane = t & 63;
  int strip = blockIdx.x * 4 + wv;
  if (strip * 16 >= n) return;
  int m = lane & 15, q = lane >> 4;
  bf16x8 Bf[4][4];
#pragma unroll
  for (int kc = 0; kc < 4; kc++)
#pragma unroll
    for (int ct = 0; ct < 4; ct++)
      Bf[kc][ct] = *(const bf16x8*)(w1t + (ct * 16 + m) * INDIM + kc * 32 + q * 8);
  const float* arow = feat + (size_t)(strip * 16 + m) * INDIM;
  bf16x8 Af[4];
#pragma unroll
  for (int kc = 0; kc < 4; kc++) {
    const float* pa = arow + kc * 32 + q * 8;
    bf16x8 a;
#pragma unroll
    for (int j = 0; j < 8; j++) a[j] = (short)f2bf(pa[j]);
    Af[kc] = a;
  }
  f32x4 acc[4] = {{0.f,0.f,0.f,0.f},{0.f,0.f,0.f,0.f},{0.f,0.f,0.f,0.f},{0.f,0.f,0.f,0.f}};
#pragma unroll
  for (int kc = 0; kc < 4; kc++)
#pragma unroll
    for (int ct = 0; ct < 4; ct++)
      acc[ct] = __builtin_amdgcn_mfma_f32_16x16x32_bf16(Af[kc], Bf[kc][ct], acc[ct], 0, 0, 0);
#pragma unroll
  for (int r = 0; r < 4; r++) {
    int row = strip * 16 + q * 4 + r;
    float nm = norm[row];
#pragma unroll
    for (int ct = 0; ct < 4; ct++)
      h0[(size_t)row * HID + ct * 16 + m] = f2fp8(acc[ct][r] * nm);
  }
}

// wave-per-node CSR gather over fp8 rows (64 B); 4 edges/iter, quarter-wave each.
// Inner loop batches 4 groups (16 edges) so bpermute+load latencies overlap.
// MODE 0: fused relu/dropout(ballot)/prescale -> fp8 out. MODE 1: raw -> bf16 out.
template <int MODE>
__global__ __launch_bounds__(256) void gather_k(const uint32_t* __restrict__ h8,
                                                void* __restrict__ outp,
                                                const int* __restrict__ rowstart,
                                                const int* __restrict__ csr,
                                                const float* __restrict__ norm,
                                                int n, uint32_t ka, uint32_t kb) {
  int d = (int)((blockIdx.x * 256 + threadIdx.x) >> 6);
  if (d >= n) return;
  int lane = threadIdx.x & 63;
  int g = lane >> 4;                     // edge group 0..3
  int c4 = lane & 15;                    // column quad
  f32x2 accl = {0.f, 0.f}, acch = {0.f, 0.f};
  if (g == 0) {                          // self loop (counted once)
    uint32_t u = h8[(size_t)d * 16 + c4];
    accl += __builtin_amdgcn_cvt_pk_f32_fp8((int)u, false);
    acch += __builtin_amdgcn_cvt_pk_f32_fp8((int)u, true);
  }
  int r0 = rowstart[d], r1 = rowstart[d + 1];
  for (int base = r0; base < r1; base += 64) {
    int m = r1 - base; if (m > 64) m = 64;
    int idx = (base + lane < r1) ? csr[base + lane] : 0;
    int nfull = m >> 2;
    int j = 0;
    // batch of 4 groups: 4 bpermutes then 4 loads in flight together
    for (; j + 4 <= nfull; j += 4) {
      int s0 = __shfl(idx, 4 * j + g);
      int s1 = __shfl(idx, 4 * j + 4 + g);
      int s2 = __shfl(idx, 4 * j + 8 + g);
      int s3 = __shfl(idx, 4 * j + 12 + g);
      uint32_t u0 = h8[(size_t)s0 * 16 + c4];
      uint32_t u1 = h8[(size_t)s1 * 16 + c4];
      uint32_t u2 = h8[(size_t)s2 * 16 + c4];
      uint32_t u3 = h8[(size_t)s3 * 16 + c4];
      accl += __builtin_amdgcn_cvt_pk_f32_fp8((int)u0, false);
      acch += __builtin_amdgcn_cvt_pk_f32_fp8((int)u0, true);
      accl += __builtin_amdgcn_cvt_pk_f32_fp8((int)u1, false);
      acch += __builtin_amdgcn_cvt_pk_f32_fp8((int)u1, true);
      accl += __builtin_amdgcn_cvt_pk_f32_fp8((int)u2, false);
      acch += __builtin_amdgcn_cvt_pk_f32_fp8((int)u2, true);
      accl += __builtin_amdgcn_cvt_pk_f32_fp8((int)u3, false);
      acch += __builtin_amdgcn_cvt_pk_f32_fp8((int)u3, true);
    }
    for (; j < nfull; j++) {
      int s = __shfl(idx, 4 * j + g);
      uint32_t u = h8[(size_t)s * 16 + c4];
      accl += __builtin_amdgcn_cvt_pk_f32_fp8((int)u, false);
      acch += __builtin_amdgcn_cvt_pk_f32_fp8((int)u, true);
    }
    int rem = m & 3;
    if (rem) {
      int s = __shfl(idx, 4 * nfull + g);
      if (g < rem) {
        uint32_t u = h8[(size_t)s * 16 + c4];
        accl += __builtin_amdgcn_cvt_pk_f32_fp8((int)u, false);
        acch += __builtin_amdgcn_cvt_pk_f32_fp8((int)u, true);
      }
    }
  }
  float a0 = accl.x, a1 = accl.y, a2 = acch.x, a3 = acch.y;
  a0 += __shfl_xor(a0, 16); a1 += __shfl_xor(a1, 16);
  a2 += __shfl_xor(a2, 16); a3 += __shfl_xor(a3, 16);
  a0 += __shfl_xor(a0, 32); a1 += __shfl_xor(a1, 32);
  a2 += __shfl_xor(a2, 32); a3 += __shfl_xor(a3, 32);
  if (MODE == 0) {
    float nm = norm[d];
    float u = tf_uniform(ka, kb, (uint32_t)d * 64u + (uint32_t)lane);
    unsigned long long keep = __ballot(u < 0.5f);
    uint32_t kb4 = (uint32_t)(keep >> (4 * c4)) & 15u;
    float v0 = fmaxf(a0 * nm, 0.f), v1 = fmaxf(a1 * nm, 0.f);
    float v2 = fmaxf(a2 * nm, 0.f), v3 = fmaxf(a3 * nm, 0.f);
    float s2 = 2.f * nm;
    v0 = (kb4 & 1u) ? v0 * s2 : 0.f;
    v1 = (kb4 & 2u) ? v1 * s2 : 0.f;
    v2 = (kb4 & 4u) ? v2 * s2 : 0.f;
    v3 = (kb4 & 8u) ? v3 * s2 : 0.f;
    if (g == 0) {
      int o = __builtin_amdgcn_cvt_pk_fp8_f32(v0, v1, 0, false);
      o = __builtin_amdgcn_cvt_pk_fp8_f32(v2, v3, o, true);
      ((uint32_t*)outp)[(size_t)d * 16 + c4] = (uint32_t)o;
    }
  } else {
    if (g == 0) {
      uint2 w;
      w.x = (uint32_t)f2bf(a0) | ((uint32_t)f2bf(a1) << 16);
      w.y = (uint32_t)f2bf(a2) | ((uint32_t)f2bf(a3) << 16);
      ((uint2*)outp)[(size_t)d * 16 + c4] = w;
    }
  }
}

// MFMA gemm2: h2 = bf16 dropout(relu(norm * (aggbf @ w2))). One wave/strip.
__global__ __launch_bounds__(256) void gemm2(const unsigned short* __restrict__ aggbf,
                                             const unsigned short* __restrict__ w2t,
                                             const float* __restrict__ norm,
                                             unsigned short* __restrict__ h2, int n,
                                             uint32_t ka, uint32_t kb) {
  int t = threadIdx.x;
  int wv = t >> 6, lane = t & 63;
  int strip = blockIdx.x * 4 + wv;
  if (strip * 16 >= n) return;
  int m = lane & 15, q = lane >> 4;
  bf16x8 Bf[2][4];
#pragma unroll
  for (int kc = 0; kc < 2; kc++)
#pragma unroll
    for (int ct = 0; ct < 4; ct++)
      Bf[kc][ct] = *(const bf16x8*)(w2t + (ct * 16 + m) * HID + kc * 32 + q * 8);
  const unsigned short* arow = aggbf + (size_t)(strip * 16 + m) * HID;
  bf16x8 Af[2];
#pragma unroll
  for (int kc = 0; kc < 2; kc++)
    Af[kc] = *(const bf16x8*)(arow + kc * 32 + q * 8);
  f32x4 acc[4] = {{0.f,0.f,0.f,0.f},{0.f,0.f,0.f,0.f},{0.f,0.f,0.f,0.f},{0.f,0.f,0.f,0.f}};
#pragma unroll
  for (int kc = 0; kc < 2; kc++)
#pragma unroll
    for (int ct = 0; ct < 4; ct++)
      acc[ct] = __builtin_amdgcn_mfma_f32_16x16x32_bf16(Af[kc], Bf[kc][ct], acc[ct], 0, 0, 0);
#pragma unroll
  for (int r = 0; r < 4; r++) {
    int row = strip * 16 + q * 4 + r;
    float nm = norm[row];
#pragma unroll
    for (int ct = 0; ct < 4; ct++) {
      int col = ct * 16 + m;
      float v = fmaxf(acc[ct][r] * nm, 0.f);
      float u = tf_uniform(ka, kb, (uint32_t)row * 64u + (uint32_t)col);
      v = (u < 0.5f) ? v * 2.f : 0.f;
      h2[(size_t)row * HID + col] = f2bf(v);
    }
  }
}

// column sums over bf16 h2 (read as packed uints)
__global__ __launch_bounds__(256) void colsum_k(const uint32_t* __restrict__ h2u,
                                                float* __restrict__ colsum, int n) {
  int t = threadIdx.x;
  int cp = t & 31;                // column pair
  int rg = t >> 5;                // 8 row groups
  float sx = 0.f, sy = 0.f;
  for (int r = blockIdx.x * 8 + rg; r < n; r += gridDim.x * 8) {
    uint32_t u = h2u[(size_t)r * 32 + cp];
    sx += bf2f_lo(u); sy += bf2f_hi(u);
  }
  __shared__ float red[8][HID];
  red[rg][2 * cp] = sx; red[rg][2 * cp + 1] = sy;
  __syncthreads();
  if (t < HID) {
    float v = 0.f;
#pragma unroll
    for (int i = 0; i < 8; i++) v += red[i][t];
    atomicAdd(&colsum[t], v);
  }
}

__global__ __launch_bounds__(128) void final_k(const uint32_t* __restrict__ h2u,
                                               const float* __restrict__ colsum,
                                               const float* __restrict__ conv_w,
                                               const float* __restrict__ conv_b,
                                               const float* __restrict__ ref_radius,
                                               float* __restrict__ out, int n) {
  __shared__ float rows[128 * 67];
  __shared__ float omean[124];
  __shared__ float cm[HID];
  int t = threadIdx.x;
  int node0 = blockIdx.x * 128;
  if (t < HID) cm[t] = colsum[t] * (1.0f / (float)n);
  for (int idx = t; idx < 128 * 32; idx += 128) {
    int r = idx >> 5, cpi = idx & 31;
    int node = node0 + r;
    uint32_t u = (node < n) ? h2u[(size_t)node * 32 + cpi] : 0u;
    rows[r * 67 + 2 * cpi] = bf2f_lo(u);
    rows[r * 67 + 2 * cpi + 1] = bf2f_hi(u);
  }
  __syncthreads();
  if (t < 124) {
    int o = t / 62, i = t % 62;
    omean[t] = conv_b[o] + conv_w[o * 3] * cm[i] + conv_w[o * 3 + 1] * cm[i + 1] +
               conv_w[o * 3 + 2] * cm[i + 2];
  }
  __syncthreads();
  int node = node0 + t;
  if (node < n) {
    float r0[HID];
#pragma unroll
    for (int k = 0; k < HID; k++) r0[k] = rows[t * 67 + k];
    float w00 = conv_w[0], w01 = conv_w[1], w02 = conv_w[2];
    float w10 = conv_w[3], w11 = conv_w[4], w12 = conv_w[5];
    float b0 = conv_b[0], b1 = conv_b[1];
    float acc = 0.f;
#pragma unroll
    for (int i = 0; i < 62; i++) {
      float y0 = b0 + w00 * r0[i] + w01 * r0[i + 1] + w02 * r0[i + 2];
      float d0 = y0 - omean[i] + 1e-6f;
      acc += d0 * d0;
      float y1 = b1 + w10 * r0[i] + w11 * r0[i + 1] + w12 * r0[i + 2];
      float d1 = y1 - omean[62 + i] + 1e-6f;
      acc += d1 * d1;
    }
    float radius = sqrtf(acc);
    float dis = fminf(fmaxf(radius - ref_radius[0], 1e-4f), 1.f - 1e-4f);
    out[node] = dis;
  }
  if (blockIdx.x == 0 && t == 0) out[n] = ref_radius[0];
}

extern "C" void kernel_launch(void* const* d_in, const int* in_sizes, int n_in,
                              void* d_out, int out_size, void* d_ws, size_t ws_size,
                              hipStream_t stream) {
  const float* feat = (const float*)d_in[0];
  const float* w1 = (const float*)d_in[1];
  const float* w2 = (const float*)d_in[2];
  const float* conv_w = (const float*)d_in[3];
  const float* conv_b = (const float*)d_in[4];
  const float* ref_radius = (const float*)d_in[5];
  const int* src = (const int*)d_in[6];
  const int* dst = (const int*)d_in[7];
  int n = in_sizes[0] / INDIM;
  int E = in_sizes[6];
  float* out = (float*)d_out;

  int NB = (n + 255) >> 8;                 // 391 buckets of 256 nodes
  int EPB = (E + NBLK - 1) / NBLK;         // 3125 edges per binsort block

  char* p = (char*)d_ws;
  auto carve = [&](size_t bytes) { void* r = (void*)p; p += (bytes + 255) & ~(size_t)255; return r; };
  float* norm = (float*)carve((size_t)n * 4);
  float* colsum = (float*)carve(HID * 4);
  int* rowstart = (int*)carve(((size_t)n + 1) * 4);
  int* bucketstart = (int*)carve(((size_t)NB + 1) * 4);
  int* totals = (int*)carve((size_t)NB * 4);
  int* blockoff = (int*)carve((size_t)NBLK * (NB + 1) * 4);
  int* destoff = (int*)carve((size_t)NBLK * NB * 4);
  uint32_t* sorted = (uint32_t*)carve((size_t)E * 4);
  uint32_t* sorted2 = (uint32_t*)carve((size_t)E * 4);
  int* csr = (int*)carve((size_t)E * 4);
  unsigned short* w1t = (unsigned short*)carve((size_t)INDIM * HID * 2);
  unsigned short* w2t = (unsigned short*)carve((size_t)HID * HID * 2);
  unsigned char* H0f8 = (unsigned char*)carve((size_t)n * HID);
  unsigned char* Tf8 = (unsigned char*)carve((size_t)n * HID);
  unsigned short* Abf = (unsigned short*)carve((size_t)n * HID * 2);
  unsigned short* H2bf = (unsigned short*)carve((size_t)n * HID * 2);

  uint32_t k1a, k1b, k2a, k2b;
  tf2x32(0u, 42u, 0u, 0u, k1a, k1b);
  tf2x32(0u, 42u, 0u, 1u, k2a, k2b);

  int gatherB = (n * 64 + 255) / 256;      // wave per node
  int stripB = ((n + 15) / 16 + 3) / 4;    // wave per 16-node strip

  binsort_k<<<NBLK, 256, 0, stream>>>(src, dst, sorted, blockoff, E, EPB, NB);
  boff_k<<<NB, NBLK, 0, stream>>>(blockoff, destoff, totals, NB);
  bscan_k<<<1, 512, 0, stream>>>(totals, bucketstart, colsum, NB, E);
  scatter2_k<<<NBLK, 256, 0, stream>>>(sorted, blockoff, destoff, bucketstart, sorted2, EPB, NB);
  csrbuild_k<<<NB, 256, 0, stream>>>(sorted2, bucketstart, rowstart, csr, norm, NB, n, E);
  wcvt_k<<<(INDIM * HID + HID * HID + 255) / 256, 256, 0, stream>>>(w1, w2, w1t, w2t);
  gemm1<<<stripB, 256, 0, stream>>>(feat, w1t, norm, H0f8, n);
  gather_k<0><<<gatherB, 256, 0, stream>>>((const uint32_t*)H0f8, Tf8, rowstart, csr, norm, n, k1a, k1b);
  gather_k<1><<<gatherB, 256, 0, stream>>>((const uint32_t*)Tf8, Abf, rowstart, csr, norm, n, 0u, 0u);
  gemm2<<<stripB, 256, 0, stream>>>(Abf, w2t, norm, H2bf, n, k2a, k2b);
  colsum_k<<<256, 256, 0, stream>>>((const uint32_t*)H2bf, colsum, n);
  final_k<<<(n + 127) / 128, 128, 0, stream>>>((const uint32_t*)H2bf, colsum, conv_w, conv_b, ref_radius, out, n);
}